// Round 9
// baseline (256.025 us; speedup 1.0000x reference)
//
#include <hip/hip_runtime.h>
#include <hip/hip_bf16.h>

#define IN_DIMX 135909
#define OUT_DIMX 670091
#define DDIM 128
#define BATCH 256
#define TFEAT 100
#define NBLK 512                      // k_lse grid: exactly 2 blocks/CU, no tail quantization
#define NCHUNK ((OUT_DIMX + 63) / 64) // 10471 chunks of 64 classes

typedef __bf16 bf16_t;
typedef __attribute__((ext_vector_type(8))) __bf16 bf16x8;
typedef __attribute__((ext_vector_type(4))) float f32x4;

// ---------------- K1: embedding bag sum -> L2 normalize -> +bias -> relu ----
__global__ void k_query(const int* __restrict__ x, const float* __restrict__ emb,
                        const float* __restrict__ bias, float* __restrict__ qf,
                        bf16_t* __restrict__ qb) {
    const int row = blockIdx.x;
    const int t = threadIdx.x; // 128 threads, one per dim
    __shared__ int sidx[TFEAT];
    if (t < TFEAT) sidx[t] = x[row * TFEAT + t];
    __syncthreads();
    float s = 0.f;
    #pragma unroll 10
    for (int i = 0; i < TFEAT; ++i) {
        s += emb[(size_t)sidx[i] * DDIM + t];
    }
    float sq = s * s;
    #pragma unroll
    for (int off = 1; off < 64; off <<= 1) sq += __shfl_xor(sq, off, 64);
    __shared__ float wred[2];
    if ((threadIdx.x & 63) == 0) wred[threadIdx.x >> 6] = sq;
    __syncthreads();
    const float tot = wred[0] + wred[1];
    float q = s / sqrtf(tot) + bias[t];
    q = fmaxf(q, 0.f);
    qf[row * DDIM + t] = q;
    qb[row * DDIM + t] = (bf16_t)q;
}

// ---------------- K2: MFMA logits + per-block partial sum-of-exp ------------
// Sync-free streaming variant: NO LDS, NO barriers. Each wave loads its MFMA
// B-fragments directly from global into registers (lane l: class row =
// cbase+nt*16+(l&15), k-cols ks*32+8*(l>>4)+[0..8) — identical logical
// mapping to the previous LDS path), cvt f32->bf16 in-reg, 16 MFMA per nt,
// exp-consume immediately. The block's 4 waves stream the same chunk ~in
// lockstep-free fashion; L2 absorbs the 4x intra-block re-read (HBM sees W
// once). Waves never synchronize -> the CU scheduler interleaves 8 waves'
// vmcnt waits freely (pure streaming regime).
__global__ __launch_bounds__(256, 2)
void k_lse(const float* __restrict__ W, const float* __restrict__ b_out,
           const bf16_t* __restrict__ qb, float* __restrict__ partials) {
    const int tid = threadIdx.x;
    const int lane = tid & 63;
    const int w = tid >> 6;
    const int l15 = lane & 15;
    const int l4 = lane >> 4;

    // A fragments: this wave's 64 batch rows (constant for whole kernel)
    bf16x8 a[4][4];
    #pragma unroll
    for (int mt = 0; mt < 4; ++mt)
        #pragma unroll
        for (int ks = 0; ks < 4; ++ks)
            a[mt][ks] = *(const bf16x8*)(qb + (w * 64 + mt * 16 + l15) * DDIM + ks * 32 + 8 * l4);

    float rs[4][4];
    #pragma unroll
    for (int mt = 0; mt < 4; ++mt)
        #pragma unroll
        for (int r = 0; r < 4; ++r) rs[mt][r] = 0.f;

    for (int ch = blockIdx.x; ch < NCHUNK; ch += NBLK) {
        const int cbase = ch * 64;
        const bool full = (cbase + 64 <= OUT_DIMX);
        #pragma unroll
        for (int nt = 0; nt < 4; ++nt) {
            int row = cbase + nt * 16 + l15;
            const bool valid = (row < OUT_DIMX);
            row = valid ? row : 0; // clamp: unconditional, in-bounds
            const float* bp = W + (size_t)row * DDIM + 8 * l4;
            // load this lane's 4 ks-fragments: 8x dwordx4, scattered over 16
            // consecutive rows (all 64B lines fully consumed by the 16-lane group)
            f32x4 lo[4], hi[4];
            #pragma unroll
            for (int ks = 0; ks < 4; ++ks) {
                lo[ks] = *(const f32x4*)(bp + ks * 32);
                hi[ks] = *(const f32x4*)(bp + ks * 32 + 4);
            }
            const float bo = b_out[row];
            f32x4 acc[4];
            #pragma unroll
            for (int mt = 0; mt < 4; ++mt) acc[mt] = (f32x4){0.f, 0.f, 0.f, 0.f};
            #pragma unroll
            for (int ks = 0; ks < 4; ++ks) {
                bf16x8 b;
                b[0] = (bf16_t)lo[ks][0]; b[1] = (bf16_t)lo[ks][1];
                b[2] = (bf16_t)lo[ks][2]; b[3] = (bf16_t)lo[ks][3];
                b[4] = (bf16_t)hi[ks][0]; b[5] = (bf16_t)hi[ks][1];
                b[6] = (bf16_t)hi[ks][2]; b[7] = (bf16_t)hi[ks][3];
                #pragma unroll
                for (int mt = 0; mt < 4; ++mt)
                    acc[mt] = __builtin_amdgcn_mfma_f32_16x16x32_bf16(
                        a[mt][ks], b, acc[mt], 0, 0, 0);
            }
            if (full) {
                #pragma unroll
                for (int mt = 0; mt < 4; ++mt)
                    #pragma unroll
                    for (int r = 0; r < 4; ++r)
                        rs[mt][r] += __expf(acc[mt][r] + bo);
            } else { // single partial tail chunk
                #pragma unroll
                for (int mt = 0; mt < 4; ++mt)
                    #pragma unroll
                    for (int r = 0; r < 4; ++r)
                        rs[mt][r] += valid ? __expf(acc[mt][r] + bo) : 0.f;
            }
        }
    }

    // reduce across the 16 lanes sharing each batch row; transposed layout
    // partials[row * NBLK + blk] so k_rowlse reads coalesced.
    #pragma unroll
    for (int mt = 0; mt < 4; ++mt)
        #pragma unroll
        for (int r = 0; r < 4; ++r) {
            float v = rs[mt][r];
            v += __shfl_xor(v, 1, 64);
            v += __shfl_xor(v, 2, 64);
            v += __shfl_xor(v, 4, 64);
            v += __shfl_xor(v, 8, 64);
            if (l15 == 0) {
                const int rowb = w * 64 + mt * 16 + l4 * 4 + r;
                partials[(size_t)rowb * NBLK + blockIdx.x] = v;
            }
        }
}

// ---------------- K3: per-row logsumexp + label logit -> per-row loss -------
__global__ void k_rowlse(const float* __restrict__ partials,
                         const int* __restrict__ y,
                         const float* __restrict__ qf,
                         const float* __restrict__ W,
                         const float* __restrict__ b_out,
                         float* __restrict__ rowloss) {
    const int i = blockIdx.x;     // batch row
    const int lane = threadIdx.x; // 64
    float s = 0.f;
    #pragma unroll
    for (int k = 0; k < NBLK / 64; ++k)
        s += partials[(size_t)i * NBLK + k * 64 + lane];
    // label logit: dot(q_i, W[y_i]) fused here
    const int yi = y[i];
    const float* wrow = W + (size_t)yi * DDIM;
    const float* qrow = qf + i * DDIM;
    float d = qrow[lane] * wrow[lane] + qrow[lane + 64] * wrow[lane + 64];
    #pragma unroll
    for (int off = 1; off < 64; off <<= 1) {
        s += __shfl_xor(s, off, 64);
        d += __shfl_xor(d, off, 64);
    }
    if (lane == 0) rowloss[i] = logf(s) - (d + b_out[yi]);
}

// ---------------- K4: mean over batch -> scalar loss ------------------------
__global__ void k_final(const float* __restrict__ rowloss, float* __restrict__ out) {
    const int i = threadIdx.x; // 256
    float t = rowloss[i];
    #pragma unroll
    for (int off = 1; off < 64; off <<= 1) t += __shfl_xor(t, off, 64);
    __shared__ float wred[4];
    if ((threadIdx.x & 63) == 0) wred[threadIdx.x >> 6] = t;
    __syncthreads();
    if (threadIdx.x == 0)
        out[0] = (wred[0] + wred[1] + wred[2] + wred[3]) * (1.0f / (float)BATCH);
}

extern "C" void kernel_launch(void* const* d_in, const int* in_sizes, int n_in,
                              void* d_out, int out_size, void* d_ws, size_t ws_size,
                              hipStream_t stream) {
    const int*   x     = (const int*)d_in[0];
    const int*   y     = (const int*)d_in[1];
    // d_in[2] = freeze, d_in[3] = slide (unused: exact/full softmax path)
    const float* emb   = (const float*)d_in[4];
    const float* bias  = (const float*)d_in[5];
    const float* W     = (const float*)d_in[6];
    const float* b_out = (const float*)d_in[7];
    float* out = (float*)d_out;

    char* ws = (char*)d_ws;
    bf16_t* qb       = (bf16_t*)(ws);           // 256*128*2 = 64 KB
    float*  qf       = (float*)(ws + 65536);    // 256*128*4 = 128 KB
    float*  rowloss  = (float*)(ws + 197632);   // 1 KB
    float*  partials = (float*)(ws + 262144);   // 256*NBLK*4 = 512 KB

    k_query<<<BATCH, DDIM, 0, stream>>>(x, emb, bias, qf, qb);
    k_lse<<<NBLK, 256, 0, stream>>>(W, b_out, qb, partials);
    k_rowlse<<<BATCH, 64, 0, stream>>>(partials, y, qf, W, b_out, rowloss);
    k_final<<<1, 256, 0, stream>>>(rowloss, out);
}

// Round 10
// 92.666 us; speedup vs baseline: 2.7629x; 2.7629x over previous
//
#include <hip/hip_runtime.h>
#include <hip/hip_bf16.h>

#define IN_DIMX 135909
#define OUT_DIMX 670091
#define DDIM 128
#define BATCH 256
#define TFEAT 100
#define NBLK 512                      // k_lse grid: exactly 2 blocks/CU, no tail quantization
#define NCHUNK ((OUT_DIMX + 63) / 64) // 10471 chunks of 64 classes

typedef __bf16 bf16_t;
typedef __attribute__((ext_vector_type(8))) __bf16 bf16x8;
typedef __attribute__((ext_vector_type(4))) __bf16 bf16x4;
typedef __attribute__((ext_vector_type(4))) float f32x4;

// ---------------- K1: embedding bag sum -> L2 normalize -> +bias -> relu ----
// 256 threads: feature list split 2-way (two 50-deep gather chains per dim)
// -> half the latency chain of the old 128-thread version. Also re-zeroes the
// completion counter used by the fused k_rowlse (runs before it every call).
__global__ void k_query(const int* __restrict__ x, const float* __restrict__ emb,
                        const float* __restrict__ bias, float* __restrict__ qf,
                        bf16_t* __restrict__ qb, int* __restrict__ counter) {
    const int row = blockIdx.x;
    const int tid = threadIdx.x;  // 0..255
    const int t = tid & 127;      // dim
    const int h = tid >> 7;       // feature half
    if (row == 0 && tid == 0) *counter = 0;
    __shared__ int sidx[TFEAT];
    if (tid < TFEAT) sidx[tid] = x[row * TFEAT + tid];
    __syncthreads();
    float s = 0.f;
    #pragma unroll 10
    for (int i = h * 50; i < h * 50 + 50; ++i)
        s += emb[(size_t)sidx[i] * DDIM + t];
    __shared__ float part[2][DDIM];
    part[h][t] = s;
    __syncthreads();
    const float s2 = part[0][t] + part[1][t]; // all 256 threads (each dim twice)
    float sq = s2 * s2;
    #pragma unroll
    for (int off = 1; off < 64; off <<= 1) sq += __shfl_xor(sq, off, 64);
    __shared__ float wred[4];
    if ((tid & 63) == 0) wred[tid >> 6] = sq;
    __syncthreads();
    const float tot = (wred[0] + wred[1] + wred[2] + wred[3]) * 0.5f; // each dim counted 2x
    if (h == 0) {
        float q = s2 / sqrtf(tot) + bias[t];
        q = fmaxf(q, 0.f);
        qf[row * DDIM + t] = q;
        qb[row * DDIM + t] = (bf16_t)q;
    }
}

// ---------------- K2: MFMA logits + per-block partial sum-of-exp ------------
// R8 anchor, UNCHANGED (proven 89.0us total): fused convwrite+reload (wr[j]
// reused in place, zero extra registers) + RAW barrier (lgkmcnt(0) only, no
// vmcnt drain) so the next chunk's 8 loads are issued BEFORE the barrier and
// stay in flight across it.
__global__ __launch_bounds__(256, 2)
void k_lse(const float* __restrict__ W, const float* __restrict__ b_out,
           const bf16_t* __restrict__ qb, float* __restrict__ partials) {
    __shared__ bf16_t lds[2][64 * DDIM]; // 2 x 16 KB bf16
    const int tid = threadIdx.x;
    const int lane = tid & 63;
    const int w = tid >> 6;
    const int l15 = lane & 15;
    const int l4 = lane >> 4;

    // A fragments: this wave's 64 batch rows (constant for whole kernel)
    bf16x8 a[4][4];
    #pragma unroll
    for (int mt = 0; mt < 4; ++mt)
        #pragma unroll
        for (int ks = 0; ks < 4; ++ks)
            a[mt][ks] = *(const bf16x8*)(qb + (w * 64 + mt * 16 + l15) * DDIM + ks * 32 + 8 * l4);

    float rs[4][4];
    #pragma unroll
    for (int mt = 0; mt < 4; ++mt)
        #pragma unroll
        for (int r = 0; r < 4; ++r) rs[mt][r] = 0.f;

    // staging geometry: thread covers f32 elems (row = j*8 + tid>>5,
    // cols [(tid&31)*4, +4)); global access per j = contiguous 1KB/wave.
    const int srow = tid >> 5;
    const int scol = (tid & 31) * 4;
    const int c16  = (tid & 31) >> 1;  // dest 16B slot within row
    const int half = (tid & 1) * 4;    // bf16 offset within slot

    f32x4 wr[8];
    float bo_n[4];

    auto issue = [&](int ch) {
        const int cb = ch * 64;
        #pragma unroll
        for (int j = 0; j < 8; ++j) {
            int r = cb + j * 8 + srow;
            r = (r < OUT_DIMX) ? r : 0; // clamp: unconditional, in-bounds
            wr[j] = *(const f32x4*)(W + (size_t)r * DDIM + scol);
        }
        #pragma unroll
        for (int nt = 0; nt < 4; ++nt) {
            int cc = cb + nt * 16 + l15;
            cc = (cc < OUT_DIMX) ? cc : 0;
            bo_n[nt] = b_out[cc];
        }
    };

    // Fused: for each j, convert+ds_write wr[j] then immediately reload wr[j]
    // with the next chunk's row j. Loads issue interleaved with ds_writes,
    // BEFORE the barrier, and ride across it (raw barrier, no vmcnt drain).
    auto convwrite_reload = [&](int cur, bool has_next, int nch) {
        const int cb = nch * 64;
        #pragma unroll
        for (int j = 0; j < 8; ++j) {
            const int row = j * 8 + srow;
            const int sp = row * 16 + (c16 ^ (row & 7));
            bf16x4 v;
            v[0] = (bf16_t)wr[j][0]; v[1] = (bf16_t)wr[j][1];
            v[2] = (bf16_t)wr[j][2]; v[3] = (bf16_t)wr[j][3];
            *(bf16x4*)(&lds[cur][sp * 8 + half]) = v;
            if (has_next) {
                int r = cb + j * 8 + srow;
                r = (r < OUT_DIMX) ? r : 0;
                wr[j] = *(const f32x4*)(W + (size_t)r * DDIM + scol);
            }
        }
    };

    int cur = 0;
    issue(blockIdx.x);
    for (int ch = blockIdx.x; ch < NCHUNK; ch += NBLK) {
        float bo_c[4];
        #pragma unroll
        for (int nt = 0; nt < 4; ++nt) bo_c[nt] = bo_n[nt];

        const bool has_next = (ch + NBLK < NCHUNK);
        convwrite_reload(cur, has_next, has_next ? ch + NBLK : 0);
        if (has_next) { // next chunk's b_out (tiny, rides with the W loads)
            const int cb = (ch + NBLK) * 64;
            #pragma unroll
            for (int nt = 0; nt < 4; ++nt) {
                int cc = cb + nt * 16 + l15;
                cc = (cc < OUT_DIMX) ? cc : 0;
                bo_n[nt] = b_out[cc];
            }
        }
        // RAW barrier: wait only LDS writes; W loads stay in flight across it.
        asm volatile("s_waitcnt lgkmcnt(0)" ::: "memory");
        __builtin_amdgcn_s_barrier();
        asm volatile("" ::: "memory"); // compiler fence: no ds_read hoist above barrier

        f32x4 acc[4][4];
        #pragma unroll
        for (int mt = 0; mt < 4; ++mt)
            #pragma unroll
            for (int nt = 0; nt < 4; ++nt) acc[mt][nt] = (f32x4){0.f, 0.f, 0.f, 0.f};

        #pragma unroll
        for (int ks = 0; ks < 4; ++ks) {
            #pragma unroll
            for (int nt = 0; nt < 4; ++nt) {
                const int row = nt * 16 + l15;
                const int sp = row * 16 + ((ks * 4 + l4) ^ (row & 7));
                const bf16x8 b = *(const bf16x8*)(&lds[cur][sp * 8]);
                #pragma unroll
                for (int mt = 0; mt < 4; ++mt)
                    acc[mt][nt] = __builtin_amdgcn_mfma_f32_16x16x32_bf16(
                        a[mt][ks], b, acc[mt][nt], 0, 0, 0);
            }
        }

        const int cbase = ch * 64;
        if (cbase + 64 <= OUT_DIMX) { // full chunk: no masking
            #pragma unroll
            for (int nt = 0; nt < 4; ++nt)
                #pragma unroll
                for (int mt = 0; mt < 4; ++mt)
                    #pragma unroll
                    for (int r = 0; r < 4; ++r)
                        rs[mt][r] += __expf(acc[mt][nt][r] + bo_c[nt]);
        } else { // single partial tail chunk
            #pragma unroll
            for (int nt = 0; nt < 4; ++nt) {
                const bool valid = (cbase + nt * 16 + l15 < OUT_DIMX);
                #pragma unroll
                for (int mt = 0; mt < 4; ++mt)
                    #pragma unroll
                    for (int r = 0; r < 4; ++r)
                        rs[mt][r] += valid ? __expf(acc[mt][nt][r] + bo_c[nt]) : 0.f;
            }
        }
        cur ^= 1;
    }

    // reduce across the 16 lanes sharing each batch row; transposed layout
    // partials[row * NBLK + blk] so k_rowlse reads coalesced.
    #pragma unroll
    for (int mt = 0; mt < 4; ++mt)
        #pragma unroll
        for (int r = 0; r < 4; ++r) {
            float v = rs[mt][r];
            v += __shfl_xor(v, 1, 64);
            v += __shfl_xor(v, 2, 64);
            v += __shfl_xor(v, 4, 64);
            v += __shfl_xor(v, 8, 64);
            if (l15 == 0) {
                const int rowb = w * 64 + mt * 16 + l4 * 4 + r;
                partials[(size_t)rowb * NBLK + blockIdx.x] = v;
            }
        }
}

// ---------------- K3 (fused): per-row loss; last block -> mean loss ---------
// 256 blocks x 64 threads. Each block computes rowloss[i]; the LAST block to
// finish (device-scope atomic counter, release/acquire via __threadfence)
// reduces all 256 rowloss in FIXED index/shuffle order -> deterministic.
__global__ void k_rowlse(const float* __restrict__ partials,
                         const int* __restrict__ y,
                         const float* __restrict__ qf,
                         const float* __restrict__ W,
                         const float* __restrict__ b_out,
                         float* __restrict__ rowloss,
                         int* __restrict__ counter,
                         float* __restrict__ out) {
    const int i = blockIdx.x;     // batch row
    const int lane = threadIdx.x; // 64
    float s = 0.f;
    #pragma unroll
    for (int k = 0; k < NBLK / 64; ++k)
        s += partials[(size_t)i * NBLK + k * 64 + lane];
    // label logit: dot(q_i, W[y_i]) fused here
    const int yi = y[i];
    const float* wrow = W + (size_t)yi * DDIM;
    const float* qrow = qf + i * DDIM;
    float d = qrow[lane] * wrow[lane] + qrow[lane + 64] * wrow[lane + 64];
    #pragma unroll
    for (int off = 1; off < 64; off <<= 1) {
        s += __shfl_xor(s, off, 64);
        d += __shfl_xor(d, off, 64);
    }
    if (lane == 0) rowloss[i] = logf(s) - (d + b_out[yi]);

    __threadfence(); // release rowloss[i] before the counter bump
    int old = 0;
    if (lane == 0) old = atomicAdd(counter, 1);
    old = __shfl(old, 0, 64);
    if (old == BATCH - 1) { // last block: fixed-order mean over rowloss
        __threadfence(); // acquire
        float t = 0.f;
        #pragma unroll
        for (int k = 0; k < BATCH / 64; ++k)
            t += rowloss[k * 64 + lane];
        #pragma unroll
        for (int off = 1; off < 64; off <<= 1) t += __shfl_xor(t, off, 64);
        if (lane == 0) out[0] = t * (1.0f / (float)BATCH);
    }
}

extern "C" void kernel_launch(void* const* d_in, const int* in_sizes, int n_in,
                              void* d_out, int out_size, void* d_ws, size_t ws_size,
                              hipStream_t stream) {
    const int*   x     = (const int*)d_in[0];
    const int*   y     = (const int*)d_in[1];
    // d_in[2] = freeze, d_in[3] = slide (unused: exact/full softmax path)
    const float* emb   = (const float*)d_in[4];
    const float* bias  = (const float*)d_in[5];
    const float* W     = (const float*)d_in[6];
    const float* b_out = (const float*)d_in[7];
    float* out = (float*)d_out;

    char* ws = (char*)d_ws;
    bf16_t* qb       = (bf16_t*)(ws);           // 256*128*2 = 64 KB
    float*  qf       = (float*)(ws + 65536);    // 256*128*4 = 128 KB
    int*    counter  = (int*)(ws + 196608);     // 4 B, re-zeroed by k_query each call
    float*  rowloss  = (float*)(ws + 197632);   // 1 KB
    float*  partials = (float*)(ws + 262144);   // 256*NBLK*4 = 512 KB

    k_query<<<BATCH, 256, 0, stream>>>(x, emb, bias, qf, qb, counter);
    k_lse<<<NBLK, 256, 0, stream>>>(W, b_out, qb, partials);
    k_rowlse<<<BATCH, 64, 0, stream>>>(partials, y, qf, W, b_out, rowloss, counter, out);
}

// Round 11
// 84.038 us; speedup vs baseline: 3.0465x; 1.1027x over previous
//
#include <hip/hip_runtime.h>
#include <hip/hip_bf16.h>

#define IN_DIMX 135909
#define OUT_DIMX 670091
#define DDIM 128
#define BATCH 256
#define TFEAT 100
#define NBLK 512                      // k_lse grid: exactly 2 blocks/CU
#define NCHUNK ((OUT_DIMX + 63) / 64) // 10471 chunks of 64 classes

typedef __bf16 bf16_t;
typedef __attribute__((ext_vector_type(4))) float f32x4;

// ---------------- K1: embedding bag sum -> L2 normalize -> +bias -> relu ----
// R8 form (128 threads) + fp8 pack of q for k_lse's A-side.
__global__ void k_query(const int* __restrict__ x, const float* __restrict__ emb,
                        const float* __restrict__ bias, float* __restrict__ qf,
                        unsigned char* __restrict__ q8) {
    const int row = blockIdx.x;
    const int t = threadIdx.x; // 128 threads, one per dim
    __shared__ int sidx[TFEAT];
    __shared__ float qs[DDIM];
    if (t < TFEAT) sidx[t] = x[row * TFEAT + t];
    __syncthreads();
    float s = 0.f;
    #pragma unroll 10
    for (int i = 0; i < TFEAT; ++i) {
        s += emb[(size_t)sidx[i] * DDIM + t];
    }
    float sq = s * s;
    #pragma unroll
    for (int off = 1; off < 64; off <<= 1) sq += __shfl_xor(sq, off, 64);
    __shared__ float wred[2];
    if ((t & 63) == 0) wred[t >> 6] = sq;
    __syncthreads();
    const float tot = wred[0] + wred[1];
    float q = s / sqrtf(tot) + bias[t];
    q = fmaxf(q, 0.f);
    qf[row * DDIM + t] = q;
    qs[t] = q;
    __syncthreads();
    if (t < 32) { // pack 4 dims/thread into fp8 e4m3
        int p = __builtin_amdgcn_cvt_pk_fp8_f32(qs[4 * t], qs[4 * t + 1], 0, false);
        p = __builtin_amdgcn_cvt_pk_fp8_f32(qs[4 * t + 2], qs[4 * t + 3], p, true);
        ((int*)q8)[row * 32 + t] = p;
    }
}

// ---------------- K2: MFMA logits + per-block partial sum-of-exp ------------
// R8 skeleton (proven 89.0us), staged format switched bf16 -> fp8 e4m3:
// halves LDS bytes (2x8KB buffers), halves the post-barrier ds_read burst
// (b64 vs b128), halves ds_write (b32), and halves the repack VALU (16
// cvt_pk_fp8 vs 32 scalar cvts). MFMA 16x16x32_fp8_fp8 runs at bf16 rate,
// identical fragment geometry (lane&15 = class row, K-idx = 8*(lane>>4)+j).
// LDS 8B-granule XOR swizzle: granule g of row r stored at g^(r&7) ->
// reads/writes are <=2-way bank aliased (free).
__global__ __launch_bounds__(256, 2)
void k_lse(const float* __restrict__ W, const float* __restrict__ b_out,
           const unsigned char* __restrict__ q8, float* __restrict__ partials) {
    __shared__ unsigned char lds[2][64 * DDIM]; // 2 x 8 KB fp8
    const int tid = threadIdx.x;
    const int lane = tid & 63;
    const int w = tid >> 6;
    const int l15 = lane & 15;
    const int l4 = lane >> 4;

    // A fragments: this wave's 64 batch rows, fp8 (8 bytes = i64 per frag)
    long a[4][4];
    #pragma unroll
    for (int mt = 0; mt < 4; ++mt)
        #pragma unroll
        for (int ks = 0; ks < 4; ++ks)
            a[mt][ks] = *(const long*)(q8 + (w * 64 + mt * 16 + l15) * DDIM + ks * 32 + 8 * l4);

    float rs[4][4];
    #pragma unroll
    for (int mt = 0; mt < 4; ++mt)
        #pragma unroll
        for (int r = 0; r < 4; ++r) rs[mt][r] = 0.f;

    // staging geometry: thread covers f32 elems (row = j*8 + tid>>5,
    // cols [(tid&31)*4, +4)); global access per j = contiguous 1KB/wave.
    const int srow = tid >> 5;
    const int scol4 = (tid & 31);       // 4-byte fp8 group index 0..31
    const int c8 = scol4 >> 1;          // dest 8B granule within row
    const int half = (scol4 & 1) * 4;   // byte offset within granule

    f32x4 wr[8];
    float bo_n[4];

    auto issue = [&](int ch) {
        const int cb = ch * 64;
        #pragma unroll
        for (int j = 0; j < 8; ++j) {
            int r = cb + j * 8 + srow;
            r = (r < OUT_DIMX) ? r : 0; // clamp: unconditional, in-bounds
            wr[j] = *(const f32x4*)(W + (size_t)r * DDIM + scol4 * 4);
        }
        #pragma unroll
        for (int nt = 0; nt < 4; ++nt) {
            int cc = cb + nt * 16 + l15;
            cc = (cc < OUT_DIMX) ? cc : 0;
            bo_n[nt] = b_out[cc];
        }
    };

    // Fused: per j, pack wr[j] -> 4 fp8 bytes, ds_write_b32, then immediately
    // reload wr[j] with the next chunk's row j (loads ride across the barrier).
    auto convwrite_reload = [&](int cur, bool has_next, int nch) {
        const int cb = nch * 64;
        #pragma unroll
        for (int j = 0; j < 8; ++j) {
            const int row = j * 8 + srow;
            const int sw = (c8 ^ (row & 7)) * 8 + half;
            int p = __builtin_amdgcn_cvt_pk_fp8_f32(wr[j][0], wr[j][1], 0, false);
            p = __builtin_amdgcn_cvt_pk_fp8_f32(wr[j][2], wr[j][3], p, true);
            *(int*)(&lds[cur][row * DDIM + sw]) = p;
            if (has_next) {
                int r = cb + j * 8 + srow;
                r = (r < OUT_DIMX) ? r : 0;
                wr[j] = *(const f32x4*)(W + (size_t)r * DDIM + scol4 * 4);
            }
        }
    };

    int cur = 0;
    issue(blockIdx.x);
    for (int ch = blockIdx.x; ch < NCHUNK; ch += NBLK) {
        float bo_c[4];
        #pragma unroll
        for (int nt = 0; nt < 4; ++nt) bo_c[nt] = bo_n[nt];

        const bool has_next = (ch + NBLK < NCHUNK);
        convwrite_reload(cur, has_next, has_next ? ch + NBLK : 0);
        if (has_next) { // next chunk's b_out rides with the W loads
            const int cb = (ch + NBLK) * 64;
            #pragma unroll
            for (int nt = 0; nt < 4; ++nt) {
                int cc = cb + nt * 16 + l15;
                cc = (cc < OUT_DIMX) ? cc : 0;
                bo_n[nt] = b_out[cc];
            }
        }
        // RAW barrier: wait only LDS writes; W loads stay in flight across it.
        asm volatile("s_waitcnt lgkmcnt(0)" ::: "memory");
        __builtin_amdgcn_s_barrier();
        asm volatile("" ::: "memory"); // no ds_read hoist above barrier

        f32x4 acc[4][4];
        #pragma unroll
        for (int mt = 0; mt < 4; ++mt)
            #pragma unroll
            for (int nt = 0; nt < 4; ++nt) acc[mt][nt] = (f32x4){0.f, 0.f, 0.f, 0.f};

        #pragma unroll
        for (int ks = 0; ks < 4; ++ks) {
            #pragma unroll
            for (int nt = 0; nt < 4; ++nt) {
                const int row = nt * 16 + l15;
                const int g = (ks * 4 + l4) ^ (row & 7);
                const long b = *(const long*)(&lds[cur][row * DDIM + g * 8]);
                #pragma unroll
                for (int mt = 0; mt < 4; ++mt)
                    acc[mt][nt] = __builtin_amdgcn_mfma_f32_16x16x32_fp8_fp8(
                        a[mt][ks], b, acc[mt][nt], 0, 0, 0);
            }
        }

        const int cbase = ch * 64;
        if (cbase + 64 <= OUT_DIMX) { // full chunk: no masking
            #pragma unroll
            for (int nt = 0; nt < 4; ++nt)
                #pragma unroll
                for (int mt = 0; mt < 4; ++mt)
                    #pragma unroll
                    for (int r = 0; r < 4; ++r)
                        rs[mt][r] += __expf(acc[mt][nt][r] + bo_c[nt]);
        } else { // single partial tail chunk
            #pragma unroll
            for (int nt = 0; nt < 4; ++nt) {
                const bool valid = (cbase + nt * 16 + l15 < OUT_DIMX);
                #pragma unroll
                for (int mt = 0; mt < 4; ++mt)
                    #pragma unroll
                    for (int r = 0; r < 4; ++r)
                        rs[mt][r] += valid ? __expf(acc[mt][nt][r] + bo_c[nt]) : 0.f;
            }
        }
        cur ^= 1;
    }

    // reduce across the 16 lanes sharing each batch row; transposed layout
    // partials[row * NBLK + blk] so k_rowlse reads coalesced.
    #pragma unroll
    for (int mt = 0; mt < 4; ++mt)
        #pragma unroll
        for (int r = 0; r < 4; ++r) {
            float v = rs[mt][r];
            v += __shfl_xor(v, 1, 64);
            v += __shfl_xor(v, 2, 64);
            v += __shfl_xor(v, 4, 64);
            v += __shfl_xor(v, 8, 64);
            if (l15 == 0) {
                const int rowb = w * 64 + mt * 16 + l4 * 4 + r;
                partials[(size_t)rowb * NBLK + blockIdx.x] = v;
            }
        }
}

// ---------------- K3: per-row logsumexp + label logit -> per-row loss -------
__global__ void k_rowlse(const float* __restrict__ partials,
                         const int* __restrict__ y,
                         const float* __restrict__ qf,
                         const float* __restrict__ W,
                         const float* __restrict__ b_out,
                         float* __restrict__ rowloss) {
    const int i = blockIdx.x;     // batch row
    const int lane = threadIdx.x; // 64
    float s = 0.f;
    #pragma unroll
    for (int k = 0; k < NBLK / 64; ++k)
        s += partials[(size_t)i * NBLK + k * 64 + lane];
    // label logit: dot(q_i, W[y_i]) fused here (exact f32)
    const int yi = y[i];
    const float* wrow = W + (size_t)yi * DDIM;
    const float* qrow = qf + i * DDIM;
    float d = qrow[lane] * wrow[lane] + qrow[lane + 64] * wrow[lane + 64];
    #pragma unroll
    for (int off = 1; off < 64; off <<= 1) {
        s += __shfl_xor(s, off, 64);
        d += __shfl_xor(d, off, 64);
    }
    if (lane == 0) rowloss[i] = logf(s) - (d + b_out[yi]);
}

// ---------------- K4: mean over batch -> scalar loss ------------------------
__global__ void k_final(const float* __restrict__ rowloss, float* __restrict__ out) {
    const int i = threadIdx.x; // 256
    float t = rowloss[i];
    #pragma unroll
    for (int off = 1; off < 64; off <<= 1) t += __shfl_xor(t, off, 64);
    __shared__ float wred[4];
    if ((threadIdx.x & 63) == 0) wred[threadIdx.x >> 6] = t;
    __syncthreads();
    if (threadIdx.x == 0)
        out[0] = (wred[0] + wred[1] + wred[2] + wred[3]) * (1.0f / (float)BATCH);
}

extern "C" void kernel_launch(void* const* d_in, const int* in_sizes, int n_in,
                              void* d_out, int out_size, void* d_ws, size_t ws_size,
                              hipStream_t stream) {
    const int*   x     = (const int*)d_in[0];
    const int*   y     = (const int*)d_in[1];
    // d_in[2] = freeze, d_in[3] = slide (unused: exact/full softmax path)
    const float* emb   = (const float*)d_in[4];
    const float* bias  = (const float*)d_in[5];
    const float* W     = (const float*)d_in[6];
    const float* b_out = (const float*)d_in[7];
    float* out = (float*)d_out;

    char* ws = (char*)d_ws;
    unsigned char* q8 = (unsigned char*)(ws);   // 256*128 = 32 KB fp8
    float*  qf       = (float*)(ws + 65536);    // 256*128*4 = 128 KB
    float*  rowloss  = (float*)(ws + 197632);   // 1 KB
    float*  partials = (float*)(ws + 262144);   // 256*NBLK*4 = 512 KB

    k_query<<<BATCH, DDIM, 0, stream>>>(x, emb, bias, qf, q8);
    k_lse<<<NBLK, 256, 0, stream>>>(W, b_out, q8, partials);
    k_rowlse<<<BATCH, 64, 0, stream>>>(partials, y, qf, W, b_out, rowloss);
    k_final<<<1, 256, 0, stream>>>(rowloss, out);
}